// Round 3
// baseline (148.288 us; speedup 1.0000x reference)
//
#include <hip/hip_runtime.h>
#include <math.h>

// Problem constants (fixed by reference): B=32, T=2048, D=128
constexpr int B   = 32;
constexpr int T   = 2048;
constexpr int D   = 128;
constexpr int C   = 8;          // timesteps per thread (chunk)
constexpr int NCH = T / C;      // 256 chunks per sequence
constexpr int DG  = D / 4;      // 32 groups of 4 consecutive d per thread

// R2: thread owns 4 consecutive d (all loads/stores dwordx4 = 16B/lane) and
// C=8 timesteps. Carry lookup: load neighbor chunk's 8 int4 mask words
// (independent -> 1 latency round), clz/ctz -> one dependent scalar fetch per
// d. Serial fallback only if neighbor chunk fully unobserved (P=2^-8, rare).
// Register trick: x_last overwrites v in place (equal when observed, v dead
// when not) -> only 3 live float4[8] arrays.
__global__ __launch_bounds__(256)
void linterp_kernel(const float* __restrict__ values,
                    const float* __restrict__ times,
                    const int*   __restrict__ mask,
                    float*       __restrict__ out)
{
    const int gid   = blockIdx.x * 256 + threadIdx.x;
    const int dg    = gid & (DG - 1);
    const int chunk = (gid >> 5) & (NCH - 1);   // DG = 2^5
    const int b     = gid >> 13;                // DG*NCH = 2^13

    const int d        = dg * 4;
    const int seq_base = b * T * D + d;         // element offset of (b,0,d)
    const int t0i      = chunk * C;

    // ---- load chunk into registers (24 independent dwordx4 loads) ----
    float4 xv[C], tmv[C], tlv[C];
    unsigned int mb[4] = {0u, 0u, 0u, 0u};
#pragma unroll
    for (int i = 0; i < C; ++i) {
        const int off = seq_base + (t0i + i) * D;
        xv[i]  = *(const float4*)(values + off);
        tmv[i] = *(const float4*)(times + off);
        const int4 m = *(const int4*)(mask + off);
        mb[0] |= (m.x != 0 ? 1u : 0u) << i;
        mb[1] |= (m.y != 0 ? 1u : 0u) << i;
        mb[2] |= (m.z != 0 ? 1u : 0u) << i;
        mb[3] |= (m.w != 0 ? 1u : 0u) << i;
    }

    // defaults for "no observation" match reference init values exactly:
    //   forward : x=0, t=times[b,0,d]      backward: x=0, t=times[b,T-1,d]
    const float4 t_first4 = *(const float4*)(times + seq_base);
    const float4 t_lastT4 = *(const float4*)(times + seq_base + (T - 1) * D);

    // ---- forward carry: last observed strictly before this chunk ----
    float fx[4] = {0.f, 0.f, 0.f, 0.f};
    float ft[4] = {t_first4.x, t_first4.y, t_first4.z, t_first4.w};
    if (chunk > 0) {
        unsigned int pb[4] = {0u, 0u, 0u, 0u};
#pragma unroll
        for (int i = 0; i < C; ++i) {            // prev chunk masks: independent
            const int4 m = *(const int4*)(mask + seq_base + (t0i - C + i) * D);
            pb[0] |= (m.x != 0 ? 1u : 0u) << i;
            pb[1] |= (m.y != 0 ? 1u : 0u) << i;
            pb[2] |= (m.z != 0 ? 1u : 0u) << i;
            pb[3] |= (m.w != 0 ? 1u : 0u) << i;
        }
#pragma unroll
        for (int j = 0; j < 4; ++j) {
            if (pb[j] != 0u) {
                const int idx = 31 - __builtin_clz(pb[j]);   // latest observed
                const int off = seq_base + (t0i - C + idx) * D + j;
                fx[j] = values[off]; ft[j] = times[off];
            } else {
                for (int t = t0i - C - 1; t >= 0; --t) {     // rare fallback
                    const int off = seq_base + t * D + j;
                    if (mask[off] != 0) { fx[j] = values[off]; ft[j] = times[off]; break; }
                }
            }
        }
    }

    // ---- backward carry: first observed strictly after this chunk ----
    float bx[4] = {0.f, 0.f, 0.f, 0.f};
    float bt[4] = {t_lastT4.x, t_lastT4.y, t_lastT4.z, t_lastT4.w};
    if (chunk < NCH - 1) {
        unsigned int nb[4] = {0u, 0u, 0u, 0u};
#pragma unroll
        for (int i = 0; i < C; ++i) {            // next chunk masks: independent
            const int4 m = *(const int4*)(mask + seq_base + (t0i + C + i) * D);
            nb[0] |= (m.x != 0 ? 1u : 0u) << i;
            nb[1] |= (m.y != 0 ? 1u : 0u) << i;
            nb[2] |= (m.z != 0 ? 1u : 0u) << i;
            nb[3] |= (m.w != 0 ? 1u : 0u) << i;
        }
#pragma unroll
        for (int j = 0; j < 4; ++j) {
            if (nb[j] != 0u) {
                const int idx = __builtin_ctz(nb[j]);        // earliest observed
                const int off = seq_base + (t0i + C + idx) * D + j;
                bx[j] = values[off]; bt[j] = times[off];
            } else {
                for (int t = t0i + 2 * C; t < T; ++t) {      // rare fallback
                    const int off = seq_base + t * D + j;
                    if (mask[off] != 0) { bx[j] = values[off]; bt[j] = times[off]; break; }
                }
            }
        }
    }

    // ---- forward pass: x_last (in place of v) / t_last per element ----
#pragma unroll
    for (int i = 0; i < C; ++i) {
        float* xp = (float*)&xv[i];
        const float* tp = (const float*)&tmv[i];
        float* lp = (float*)&tlv[i];
#pragma unroll
        for (int j = 0; j < 4; ++j) {
            if ((mb[j] >> i) & 1u) { fx[j] = xp[j]; ft[j] = tp[j]; }
            xp[j] = fx[j];          // x_last overwrites v (equal when observed)
            lp[j] = ft[j];
        }
    }

    // ---- reverse pass: x_next/t_next on the fly, combine, store ----
#pragma unroll
    for (int i = C - 1; i >= 0; --i) {
        const float* xp = (const float*)&xv[i];
        const float* tp = (const float*)&tmv[i];
        const float* lp = (const float*)&tlv[i];
        float4 o;
        float* op = (float*)&o;
#pragma unroll
        for (int j = 0; j < 4; ++j) {
            const bool obs = (mb[j] >> i) & 1u;
            if (obs) { bx[j] = xp[j]; bt[j] = lp[j]; }  // == v[i], tm[i]
            const float denom = bt[j] - lp[j];
            const float num   = xp[j] * (bt[j] - tp[j]) + bx[j] * (tp[j] - lp[j]);
            const bool  safe  = (denom != 0.f);
            float xi = num / (safe ? denom : 1.f);
            xi = (safe && isfinite(xi)) ? xi : 0.f;
            op[j] = obs ? xp[j] : xi;                   // xp[j]==v[i][j] when obs
        }
        *(float4*)(out + seq_base + (t0i + i) * D) = o;
    }
}

extern "C" void kernel_launch(void* const* d_in, const int* in_sizes, int n_in,
                              void* d_out, int out_size, void* d_ws, size_t ws_size,
                              hipStream_t stream)
{
    const float* values = (const float*)d_in[0];
    const float* times  = (const float*)d_in[1];
    const int*   mask   = (const int*)d_in[2];
    float*       out    = (float*)d_out;

    const int total_threads = B * NCH * DG;   // 262144
    linterp_kernel<<<total_threads / 256, 256, 0, stream>>>(values, times, mask, out);
}